// Round 1
// baseline (1781.139 us; speedup 1.0000x reference)
//
#include <hip/hip_runtime.h>
#include <hip/hip_bf16.h>

// ---------------------------------------------------------------------------
// GCN surface: 4x GCNConv(tanh) + global max/mean pool + 3-layer MLP
// Strategy:
//   - CSR by dst built on-device each call (histogram + scan + scatter)
//   - layer0 reordered: xa = A_hat @ x (128-dim gather), then GEMM+bias+tanh
//   - layers 1..3: GEMM (no bias) then fused aggregate+self+bias+tanh
//   - fp32 everywhere (threshold 7e-5 abs; bf16 too risky this round)
// ---------------------------------------------------------------------------

#define NNODES 50000
#define DDIM 256

__device__ __forceinline__ float fast_tanh(float x) {
    float e = __expf(2.0f * x);
    return 1.0f - 2.0f / (e + 1.0f);   // stable: e->inf => 1, e->0 => -1
}

__device__ __forceinline__ unsigned f2key(float f) {
    unsigned b = __float_as_uint(f);
    return (b & 0x80000000u) ? ~b : (b | 0x80000000u);
}
__device__ __forceinline__ float key2f(unsigned k) {
    unsigned b = (k & 0x80000000u) ? (k & 0x7fffffffu) : ~k;
    return __uint_as_float(b);
}

// ---------------- CSR build ----------------
__global__ void hist_kernel(const int* __restrict__ ei, int* __restrict__ deg, int E) {
    int e = blockIdx.x * blockDim.x + threadIdx.x;
    if (e < E) atomicAdd(&deg[ei[E + e]], 1);
}

__global__ void dis_kernel(const int* __restrict__ deg, float* __restrict__ dis, int N) {
    int n = blockIdx.x * blockDim.x + threadIdx.x;
    if (n < N) dis[n] = rsqrtf(1.0f + (float)deg[n]);
}

__global__ void scan_kernel(const int* __restrict__ deg, int* __restrict__ row_ptr,
                            int* __restrict__ cursor, int N) {
    const int T = 1024;
    int t = threadIdx.x;
    int chunk = (N + T - 1) / T;
    int base = t * chunk;
    int s = 0;
    for (int i = 0; i < chunk; ++i) {
        int idx = base + i;
        if (idx < N) s += deg[idx];
    }
    __shared__ int ps[T];
    ps[t] = s;
    __syncthreads();
    for (int off = 1; off < T; off <<= 1) {
        int v = (t >= off) ? ps[t - off] : 0;
        __syncthreads();
        ps[t] += v;
        __syncthreads();
    }
    int run = (t == 0) ? 0 : ps[t - 1];
    for (int i = 0; i < chunk; ++i) {
        int idx = base + i;
        if (idx < N) {
            row_ptr[idx] = run;
            cursor[idx]  = run;
            run += deg[idx];
        }
    }
}

__global__ void scatter_kernel(const int* __restrict__ ei, int* __restrict__ cursor,
                               int* __restrict__ col, float* __restrict__ normv,
                               const float* __restrict__ dis, int E) {
    int e = blockIdx.x * blockDim.x + threadIdx.x;
    if (e < E) {
        int s = ei[e];
        int d = ei[E + e];
        int p = atomicAdd(&cursor[d], 1);
        col[p]   = s;
        normv[p] = dis[s] * dis[d];
    }
}

// ---------------- message passing (one WG per dst node) ----------------
// out[n][t] = sum_{e in in(n)} norm_e * in[src_e][t] + dis[n]^2 * in[n][t]
// if FINALIZE: out = tanh(out + bias[t])
template <int D, bool FINALIZE>
__global__ void msgpass_kernel(const float* __restrict__ in, float* __restrict__ out,
                               const int* __restrict__ row_ptr, const int* __restrict__ deg,
                               const int* __restrict__ col, const float* __restrict__ normv,
                               const float* __restrict__ dis, const float* __restrict__ bias) {
    int n = blockIdx.x;
    int t = threadIdx.x;   // t < D, blockDim.x == D
    int start = row_ptr[n];
    int cnt   = deg[n];
    __shared__ int   s_col[256];
    __shared__ float s_nrm[256];
    float acc = 0.0f;
    for (int base = 0; base < cnt; base += D) {
        int m = cnt - base;
        if (m > D) m = D;
        __syncthreads();
        if (t < m) {
            s_col[t] = col[start + base + t];
            s_nrm[t] = normv[start + base + t];
        }
        __syncthreads();
        int i = 0;
        for (; i + 4 <= m; i += 4) {
            int   c0 = s_col[i],     c1 = s_col[i + 1], c2 = s_col[i + 2], c3 = s_col[i + 3];
            float w0 = s_nrm[i],     w1 = s_nrm[i + 1], w2 = s_nrm[i + 2], w3 = s_nrm[i + 3];
            float v0 = in[c0 * D + t];
            float v1 = in[c1 * D + t];
            float v2 = in[c2 * D + t];
            float v3 = in[c3 * D + t];
            acc = fmaf(v0, w0, acc);
            acc = fmaf(v1, w1, acc);
            acc = fmaf(v2, w2, acc);
            acc = fmaf(v3, w3, acc);
        }
        for (; i < m; ++i)
            acc = fmaf(in[s_col[i] * D + t], s_nrm[i], acc);
    }
    float dn = dis[n];
    acc = fmaf(in[n * D + t], dn * dn, acc);
    if (FINALIZE) acc = fast_tanh(acc + bias[t]);
    out[n * D + t] = acc;
}

// ---------------- GEMM: C[N,256] = A[N,K] * W[K,256] (+bias, tanh) ----------------
template <int KDIM, bool TANH>
__launch_bounds__(256, 2)
__global__ void gemm_kernel(const float* __restrict__ A, const float* __restrict__ W,
                            const float* __restrict__ bias, float* __restrict__ C, int N) {
    constexpr int BM = 64, BN = 256, BK = 16;
    constexpr int ASTR = 68;                 // 16B-aligned, 2-way-max bank aliasing
    __shared__ float As[BK * ASTR];
    __shared__ float Ws[BK * BN];
    int t  = threadIdx.x;
    int cg = t & 31;       // col group: cols cg*8 .. +8
    int rg = t >> 5;       // row group: rows rg*8 .. +8
    int n0 = blockIdx.x * BM;

    float acc[8][8];
#pragma unroll
    for (int i = 0; i < 8; ++i)
#pragma unroll
        for (int j = 0; j < 8; ++j) acc[i][j] = 0.0f;

    int ar = t >> 2;           // 0..63 tile row
    int ak = (t & 3) * 4;      // k offset within chunk
    int arow = n0 + ar;
    if (arow > N - 1) arow = N - 1;
    const float* Aptr = A + (size_t)arow * KDIM + ak;

    float4 a_reg;
    float4 w_reg[4];
    // prologue loads (chunk 0)
    a_reg = *(const float4*)(Aptr);
#pragma unroll
    for (int j = 0; j < 4; ++j) {
        int u = t + 256 * j;
        int k = u >> 6;
        int c = (u & 63) * 4;
        w_reg[j] = *(const float4*)(W + (size_t)k * BN + c);
    }

    const int nch = KDIM / BK;
    for (int ch = 0; ch < nch; ++ch) {
        __syncthreads();
        As[(ak + 0) * ASTR + ar] = a_reg.x;
        As[(ak + 1) * ASTR + ar] = a_reg.y;
        As[(ak + 2) * ASTR + ar] = a_reg.z;
        As[(ak + 3) * ASTR + ar] = a_reg.w;
#pragma unroll
        for (int j = 0; j < 4; ++j) {
            int u = t + 256 * j;
            int k = u >> 6;
            int c = (u & 63) * 4;
            *(float4*)&Ws[k * BN + c] = w_reg[j];
        }
        __syncthreads();
        if (ch + 1 < nch) {
            int k0 = (ch + 1) * BK;
            a_reg = *(const float4*)(Aptr + k0);
#pragma unroll
            for (int j = 0; j < 4; ++j) {
                int u = t + 256 * j;
                int k = u >> 6;
                int c = (u & 63) * 4;
                w_reg[j] = *(const float4*)(W + (size_t)(k0 + k) * BN + c);
            }
        }
#pragma unroll
        for (int kk = 0; kk < BK; ++kk) {
            float4 a0 = *(const float4*)&As[kk * ASTR + rg * 8];
            float4 a1 = *(const float4*)&As[kk * ASTR + rg * 8 + 4];
            float4 b0 = *(const float4*)&Ws[kk * BN + cg * 8];
            float4 b1 = *(const float4*)&Ws[kk * BN + cg * 8 + 4];
            float av[8] = {a0.x, a0.y, a0.z, a0.w, a1.x, a1.y, a1.z, a1.w};
            float bv[8] = {b0.x, b0.y, b0.z, b0.w, b1.x, b1.y, b1.z, b1.w};
#pragma unroll
            for (int i = 0; i < 8; ++i)
#pragma unroll
                for (int j = 0; j < 8; ++j)
                    acc[i][j] = fmaf(av[i], bv[j], acc[i][j]);
        }
    }

#pragma unroll
    for (int i = 0; i < 8; ++i) {
        int row = n0 + rg * 8 + i;
        if (row < N) {
            float4 o0, o1;
            float v[8];
#pragma unroll
            for (int j = 0; j < 8; ++j) {
                float x = acc[i][j];
                if (TANH) x = fast_tanh(x + bias[cg * 8 + j]);
                v[j] = x;
            }
            o0 = make_float4(v[0], v[1], v[2], v[3]);
            o1 = make_float4(v[4], v[5], v[6], v[7]);
            *(float4*)&C[(size_t)row * BN + cg * 8]     = o0;
            *(float4*)&C[(size_t)row * BN + cg * 8 + 4] = o1;
        }
    }
}

// ---------------- pooling (sorted batch index, run-flush) ----------------
#define POOL_CHUNK 256
__global__ void pool_kernel(const float* __restrict__ act, const int* __restrict__ batch,
                            float* __restrict__ gsum, unsigned* __restrict__ gmaxk,
                            int* __restrict__ gcnt, int N) {
    int t  = threadIdx.x;   // 256 = DDIM
    int n0 = blockIdx.x * POOL_CHUNK;
    if (n0 >= N) return;
    int n1 = n0 + POOL_CHUNK;
    if (n1 > N) n1 = N;
    int   cur = batch[n0];
    float sum = 0.0f, mx = -2.0f;
    int   run = 0;
    for (int n = n0; n < n1; ++n) {
        int g = batch[n];
        float v = act[n * DDIM + t];
        if (g != cur) {
            atomicAdd(&gsum[cur * DDIM + t], sum);
            atomicMax(&gmaxk[cur * DDIM + t], f2key(mx));
            if (t == 0) atomicAdd(&gcnt[cur], run);
            cur = g; sum = 0.0f; mx = -2.0f; run = 0;
        }
        sum += v;
        mx = fmaxf(mx, v);
        run++;
    }
    atomicAdd(&gsum[cur * DDIM + t], sum);
    atomicMax(&gmaxk[cur * DDIM + t], f2key(mx));
    if (t == 0) atomicAdd(&gcnt[cur], run);
}

// ---------------- fused MLP (one WG per graph) ----------------
__global__ void mlp_kernel(const float* __restrict__ gsum, const unsigned* __restrict__ gmaxk,
                           const int* __restrict__ gcnt,
                           const float* __restrict__ fc1_w, const float* __restrict__ fc1_b,
                           const float* __restrict__ fc2_w, const float* __restrict__ fc2_b,
                           const float* __restrict__ out_w, const float* __restrict__ out_b,
                           float* __restrict__ out) {
    int g = blockIdx.x;
    int t = threadIdx.x;   // 256
    __shared__ float gv[512];
    __shared__ float t1[512];
    __shared__ float t2[256];
    float cnt = fmaxf((float)gcnt[g], 1.0f);
    gv[t]       = key2f(gmaxk[g * DDIM + t]);      // gmax part
    gv[256 + t] = gsum[g * DDIM + t] / cnt;        // gmean part
    __syncthreads();
    float a0 = fc1_b[t], a1 = fc1_b[t + 256];
    for (int k = 0; k < 512; ++k) {
        float gk = gv[k];
        a0 = fmaf(gk, fc1_w[k * 512 + t], a0);
        a1 = fmaf(gk, fc1_w[k * 512 + t + 256], a1);
    }
    t1[t]       = fmaxf(a0, 0.0f);
    t1[t + 256] = fmaxf(a1, 0.0f);
    __syncthreads();
    float b0 = fc2_b[t];
    for (int k = 0; k < 512; ++k)
        b0 = fmaf(t1[k], fc2_w[k * 256 + t], b0);
    t2[t] = fmaxf(b0, 0.0f);
    __syncthreads();
    if (t < 10) {
        float o = out_b[t];
        for (int k = 0; k < 256; ++k)
            o = fmaf(t2[k], out_w[k * 10 + t], o);
        out[g * 10 + t] = o;
    }
}

// ---------------------------------------------------------------------------
extern "C" void kernel_launch(void* const* d_in, const int* in_sizes, int n_in,
                              void* d_out, int out_size, void* d_ws, size_t ws_size,
                              hipStream_t stream) {
    const float* x      = (const float*)d_in[0];
    const int*   ei     = (const int*)d_in[1];
    const int*   batch  = (const int*)d_in[2];
    const float* W0     = (const float*)d_in[3];
    const float* b0     = (const float*)d_in[4];
    const float* W1     = (const float*)d_in[5];
    const float* b1     = (const float*)d_in[6];
    const float* W2     = (const float*)d_in[7];
    const float* b2     = (const float*)d_in[8];
    const float* W3     = (const float*)d_in[9];
    const float* b3     = (const float*)d_in[10];
    const float* fc1_w  = (const float*)d_in[11];
    const float* fc1_b  = (const float*)d_in[12];
    const float* fc2_w  = (const float*)d_in[13];
    const float* fc2_b  = (const float*)d_in[14];
    const float* out_w  = (const float*)d_in[15];
    const float* out_b  = (const float*)d_in[16];
    float* out = (float*)d_out;

    const int N = in_sizes[2];          // 50000
    const int E = in_sizes[1] / 2;      // 1600000

    // workspace layout (bytes)
    char* ws = (char*)d_ws;
    const size_t off_deg    = 0;
    const size_t off_gsum   = 200192;
    const size_t off_gmaxk  = 265728;
    const size_t off_gcnt   = 331264;
    const size_t ZERO_BYTES = 331776;   // deg+gsum+gmaxk+gcnt contiguous
    const size_t off_dis    = 331776;
    const size_t off_rowptr = 531968;
    const size_t off_cursor = 732160;
    const size_t off_col    = 932352;
    const size_t off_norm   = 7332352;
    const size_t off_bufA   = 13732352;
    const size_t off_bufB   = 64932352;

    int*      deg    = (int*)(ws + off_deg);
    float*    gsum   = (float*)(ws + off_gsum);
    unsigned* gmaxk  = (unsigned*)(ws + off_gmaxk);
    int*      gcnt   = (int*)(ws + off_gcnt);
    float*    dis    = (float*)(ws + off_dis);
    int*      rowptr = (int*)(ws + off_rowptr);
    int*      cursor = (int*)(ws + off_cursor);
    int*      col    = (int*)(ws + off_col);
    float*    normv  = (float*)(ws + off_norm);
    float*    bufA   = (float*)(ws + off_bufA);
    float*    bufB   = (float*)(ws + off_bufB);

    hipMemsetAsync(ws, 0, ZERO_BYTES, stream);

    // CSR build
    hist_kernel<<<(E + 255) / 256, 256, 0, stream>>>(ei, deg, E);
    dis_kernel<<<(N + 255) / 256, 256, 0, stream>>>(deg, dis, N);
    scan_kernel<<<1, 1024, 0, stream>>>(deg, rowptr, cursor, N);
    scatter_kernel<<<(E + 255) / 256, 256, 0, stream>>>(ei, cursor, col, normv, dis, E);

    // layer 0 (reordered): xa = A_hat @ x  (128-dim), then tanh(xa @ W0 + b0)
    msgpass_kernel<128, false><<<N, 128, 0, stream>>>(x, bufB, rowptr, deg, col, normv, dis, nullptr);
    gemm_kernel<128, true><<<(N + 63) / 64, 256, 0, stream>>>(bufB, W0, b0, bufA, N);

    // layers 1..3: h = act @ W ; act = tanh(A_hat h + b)
    const float* Ws_[3] = {W1, W2, W3};
    const float* bs_[3] = {b1, b2, b3};
    for (int l = 0; l < 3; ++l) {
        gemm_kernel<256, false><<<(N + 63) / 64, 256, 0, stream>>>(bufA, Ws_[l], nullptr, bufB, N);
        msgpass_kernel<256, true><<<N, 256, 0, stream>>>(bufB, bufA, rowptr, deg, col, normv, dis, bs_[l]);
    }

    // pooling + MLP
    pool_kernel<<<(N + POOL_CHUNK - 1) / POOL_CHUNK, 256, 0, stream>>>(bufA, batch, gsum, gmaxk, gcnt, N);
    mlp_kernel<<<64, 256, 0, stream>>>(gsum, gmaxk, gcnt, fc1_w, fc1_b, fc2_w, fc2_b,
                                       out_w, out_b, out);
}

// Round 2
// 1024.313 us; speedup vs baseline: 1.7389x; 1.7389x over previous
//
#include <hip/hip_runtime.h>
#include <hip/hip_bf16.h>

// ---------------------------------------------------------------------------
// GCN surface: 4x GCNConv(tanh) + global max/mean pool + 3-layer MLP
// Round 2:
//   - intermediates in bf16: halves msgpass gather traffic (the #1 cost)
//   - GEMMs via mfma_f32_16x16x32_bf16 (fp32 accum), 128x128 block tile
//   - msgpass: one wave per node, wave-uniform edge loads, ushort4 gathers
//   - accuracy: network is contractive (~0.17x/layer); bf16 noise scales with
//     local signal and decays; fp32 margin was 148x, predict >=3x margin here
// ---------------------------------------------------------------------------

#define NNODES 50000
#define DDIM 256

typedef __attribute__((ext_vector_type(8))) short short8;
typedef __attribute__((ext_vector_type(4))) float float4_;

__device__ __forceinline__ float fast_tanh(float x) {
    float e = __expf(2.0f * x);
    return 1.0f - 2.0f / (e + 1.0f);
}

__device__ __forceinline__ float bf2f(unsigned short u) {
    return __uint_as_float(((unsigned)u) << 16);
}
__device__ __forceinline__ unsigned short f2bf(float f) {
    unsigned u = __float_as_uint(f);
    u = u + 0x7fffu + ((u >> 16) & 1u);   // round-to-nearest-even
    return (unsigned short)(u >> 16);
}

__device__ __forceinline__ unsigned f2key(float f) {
    unsigned b = __float_as_uint(f);
    return (b & 0x80000000u) ? ~b : (b | 0x80000000u);
}
__device__ __forceinline__ float key2f(unsigned k) {
    unsigned b = (k & 0x80000000u) ? (k & 0x7fffffffu) : ~k;
    return __uint_as_float(b);
}

// ---------------- CSR build ----------------
__global__ void hist_kernel(const int* __restrict__ ei, int* __restrict__ deg, int E) {
    int e = blockIdx.x * blockDim.x + threadIdx.x;
    if (e < E) atomicAdd(&deg[ei[E + e]], 1);
}

__global__ void dis_kernel(const int* __restrict__ deg, float* __restrict__ dis, int N) {
    int n = blockIdx.x * blockDim.x + threadIdx.x;
    if (n < N) dis[n] = rsqrtf(1.0f + (float)deg[n]);
}

__global__ void scan_kernel(const int* __restrict__ deg, int* __restrict__ row_ptr,
                            int* __restrict__ cursor, int N) {
    const int T = 1024;
    int t = threadIdx.x;
    int chunk = (N + T - 1) / T;
    int base = t * chunk;
    int s = 0;
    for (int i = 0; i < chunk; ++i) {
        int idx = base + i;
        if (idx < N) s += deg[idx];
    }
    __shared__ int ps[T];
    ps[t] = s;
    __syncthreads();
    for (int off = 1; off < T; off <<= 1) {
        int v = (t >= off) ? ps[t - off] : 0;
        __syncthreads();
        ps[t] += v;
        __syncthreads();
    }
    int run = (t == 0) ? 0 : ps[t - 1];
    for (int i = 0; i < chunk; ++i) {
        int idx = base + i;
        if (idx < N) {
            row_ptr[idx] = run;
            cursor[idx]  = run;
            run += deg[idx];
        }
    }
}

__global__ void scatter_kernel(const int* __restrict__ ei, int* __restrict__ cursor,
                               int* __restrict__ col, float* __restrict__ normv,
                               const float* __restrict__ dis, int E) {
    int e = blockIdx.x * blockDim.x + threadIdx.x;
    if (e < E) {
        int s = ei[e];
        int d = ei[E + e];
        int p = atomicAdd(&cursor[d], 1);
        col[p]   = s;
        normv[p] = dis[s] * dis[d];
    }
}

// ---------------- casts ----------------
__global__ void cast_x_kernel(const float* __restrict__ x, unsigned short* __restrict__ xh,
                              int total) {
    int i = blockIdx.x * blockDim.x + threadIdx.x;
    if (i < total) xh[i] = f2bf(x[i]);
}

// W[K][256] -> Wt[256][K] bf16
__global__ void transpose_w_kernel(const float* __restrict__ W, unsigned short* __restrict__ Wt,
                                   int K) {
    int k = blockIdx.x;      // 0..K-1
    int n = threadIdx.x;     // 0..255
    Wt[n * K + k] = f2bf(W[k * 256 + n]);
}

// ---------------- message passing: one wave per node ----------------
// out[n][f] = sum_e norm_e * in[col_e][f] + dis[n]^2 * in[n][f]  (+bias,tanh)
template <int D, bool FINALIZE>
__global__ void msgpass_bf16(const unsigned short* __restrict__ in,
                             unsigned short* __restrict__ out,
                             const int* __restrict__ rowptr, const int* __restrict__ deg,
                             const int* __restrict__ col, const float* __restrict__ normv,
                             const float* __restrict__ dis, const float* __restrict__ bias) {
    constexpr int V = D / 64;                 // features per lane (2 or 4)
    int lane = threadIdx.x & 63;
    int wav  = threadIdx.x >> 6;
    int n = blockIdx.x * 4 + wav;
    if (n >= NNODES) return;
    int start = rowptr[n];
    int cnt   = deg[n];
    float acc[V];
#pragma unroll
    for (int v = 0; v < V; ++v) acc[v] = 0.0f;

    const unsigned short* inl = in + (size_t)lane * V;

    int e = 0;
    for (; e + 4 <= cnt; e += 4) {
        int i0 = start + e;
        int c0 = col[i0], c1 = col[i0 + 1], c2 = col[i0 + 2], c3 = col[i0 + 3];
        float w0 = normv[i0], w1 = normv[i0 + 1], w2 = normv[i0 + 2], w3 = normv[i0 + 3];
        if (V == 4) {
            ushort4 u0 = *(const ushort4*)(inl + (size_t)c0 * D);
            ushort4 u1 = *(const ushort4*)(inl + (size_t)c1 * D);
            ushort4 u2 = *(const ushort4*)(inl + (size_t)c2 * D);
            ushort4 u3 = *(const ushort4*)(inl + (size_t)c3 * D);
            acc[0] = fmaf(bf2f(u0.x), w0, acc[0]); acc[1] = fmaf(bf2f(u0.y), w0, acc[1]);
            acc[2] = fmaf(bf2f(u0.z), w0, acc[2]); acc[3] = fmaf(bf2f(u0.w), w0, acc[3]);
            acc[0] = fmaf(bf2f(u1.x), w1, acc[0]); acc[1] = fmaf(bf2f(u1.y), w1, acc[1]);
            acc[2] = fmaf(bf2f(u1.z), w1, acc[2]); acc[3] = fmaf(bf2f(u1.w), w1, acc[3]);
            acc[0] = fmaf(bf2f(u2.x), w2, acc[0]); acc[1] = fmaf(bf2f(u2.y), w2, acc[1]);
            acc[2] = fmaf(bf2f(u2.z), w2, acc[2]); acc[3] = fmaf(bf2f(u2.w), w2, acc[3]);
            acc[0] = fmaf(bf2f(u3.x), w3, acc[0]); acc[1] = fmaf(bf2f(u3.y), w3, acc[1]);
            acc[2] = fmaf(bf2f(u3.z), w3, acc[2]); acc[3] = fmaf(bf2f(u3.w), w3, acc[3]);
        } else {
            ushort2 u0 = *(const ushort2*)(inl + (size_t)c0 * D);
            ushort2 u1 = *(const ushort2*)(inl + (size_t)c1 * D);
            ushort2 u2 = *(const ushort2*)(inl + (size_t)c2 * D);
            ushort2 u3 = *(const ushort2*)(inl + (size_t)c3 * D);
            acc[0] = fmaf(bf2f(u0.x), w0, acc[0]); acc[1] = fmaf(bf2f(u0.y), w0, acc[1]);
            acc[0] = fmaf(bf2f(u1.x), w1, acc[0]); acc[1] = fmaf(bf2f(u1.y), w1, acc[1]);
            acc[0] = fmaf(bf2f(u2.x), w2, acc[0]); acc[1] = fmaf(bf2f(u2.y), w2, acc[1]);
            acc[0] = fmaf(bf2f(u3.x), w3, acc[0]); acc[1] = fmaf(bf2f(u3.y), w3, acc[1]);
        }
    }
    for (; e < cnt; ++e) {
        int c = col[start + e];
        float w = normv[start + e];
        if (V == 4) {
            ushort4 u = *(const ushort4*)(inl + (size_t)c * D);
            acc[0] = fmaf(bf2f(u.x), w, acc[0]); acc[1] = fmaf(bf2f(u.y), w, acc[1]);
            acc[2] = fmaf(bf2f(u.z), w, acc[2]); acc[3] = fmaf(bf2f(u.w), w, acc[3]);
        } else {
            ushort2 u = *(const ushort2*)(inl + (size_t)c * D);
            acc[0] = fmaf(bf2f(u.x), w, acc[0]); acc[1] = fmaf(bf2f(u.y), w, acc[1]);
        }
    }
    // self loop
    {
        float dn = dis[n];
        float w = dn * dn;
        if (V == 4) {
            ushort4 u = *(const ushort4*)(inl + (size_t)n * D);
            acc[0] = fmaf(bf2f(u.x), w, acc[0]); acc[1] = fmaf(bf2f(u.y), w, acc[1]);
            acc[2] = fmaf(bf2f(u.z), w, acc[2]); acc[3] = fmaf(bf2f(u.w), w, acc[3]);
        } else {
            ushort2 u = *(const ushort2*)(inl + (size_t)n * D);
            acc[0] = fmaf(bf2f(u.x), w, acc[0]); acc[1] = fmaf(bf2f(u.y), w, acc[1]);
        }
    }
    if (FINALIZE) {
#pragma unroll
        for (int v = 0; v < V; ++v)
            acc[v] = fast_tanh(acc[v] + bias[lane * V + v]);
    }
    if (V == 4) {
        ushort4 o;
        o.x = f2bf(acc[0]); o.y = f2bf(acc[1]); o.z = f2bf(acc[2]); o.w = f2bf(acc[3]);
        *(ushort4*)(out + (size_t)n * D + lane * V) = o;
    } else {
        ushort2 o;
        o.x = f2bf(acc[0]); o.y = f2bf(acc[1]);
        *(ushort2*)(out + (size_t)n * D + lane * V) = o;
    }
}

// ---------------- MFMA GEMM: C[N,256] = A[N,K] * W[K,256] ----------------
// A: bf16 row-major [N][K]; Bt: bf16 [256][K] (W transposed, n-major);
// C: bf16 [N][256]. Block tile 128x128, 4 waves at 64x64 each.
// mfma_f32_16x16x32_bf16 layouts (m89-verified):
//   A frag: A[m=lane&15][k=(lane>>4)*8 + j]   (8 contiguous bf16)
//   B frag: B[k=(lane>>4)*8 + j][n=lane&15]   (from Bt: 8 contiguous bf16)
//   C/D   : col=lane&15, row=(lane>>4)*4 + reg
template <int K, bool TANH>
__launch_bounds__(256, 2)
__global__ void gemm_mfma(const short* __restrict__ A, const short* __restrict__ Bt,
                          const float* __restrict__ bias, unsigned short* __restrict__ C,
                          int N) {
    constexpr int PK = 40;   // padded k pitch (bf16 elems); 80B rows, 16B-aligned segs
    __shared__ __align__(16) short As[128 * PK];
    __shared__ __align__(16) short Bs[128 * PK];
    int t = threadIdx.x;
    int lane = t & 63;
    int w    = t >> 6;
    int wr = w & 1;          // row half of block tile
    int wc = w >> 1;         // col half
    int m0 = blockIdx.x * 128;
    int n0 = blockIdx.y * 128;

    // staging: thread t loads rows (t>>2) and 64+(t>>2), k-offset (t&3)*8
    int srow = t >> 2;
    int koff = (t & 3) * 8;
    int arow0 = m0 + srow;      if (arow0 > N - 1) arow0 = N - 1;
    int arow1 = m0 + 64 + srow; if (arow1 > N - 1) arow1 = N - 1;
    const short8* ap0 = (const short8*)(A + (size_t)arow0 * K + koff);
    const short8* ap1 = (const short8*)(A + (size_t)arow1 * K + koff);
    const short8* bp0 = (const short8*)(Bt + (size_t)(n0 + srow) * K + koff);
    const short8* bp1 = (const short8*)(Bt + (size_t)(n0 + 64 + srow) * K + koff);

    float4_ acc[4][4];
#pragma unroll
    for (int i = 0; i < 4; ++i)
#pragma unroll
        for (int j = 0; j < 4; ++j) {
            float4_ z = {0.0f, 0.0f, 0.0f, 0.0f};
            acc[i][j] = z;
        }

    short8 a0 = ap0[0], a1 = ap1[0], b0 = bp0[0], b1 = bp1[0];
    constexpr int NKB = K / 32;
    int g = lane >> 4;
    int r = lane & 15;

    for (int kb = 0; kb < NKB; ++kb) {
        __syncthreads();
        *(short8*)&As[srow * PK + koff]        = a0;
        *(short8*)&As[(64 + srow) * PK + koff] = a1;
        *(short8*)&Bs[srow * PK + koff]        = b0;
        *(short8*)&Bs[(64 + srow) * PK + koff] = b1;
        __syncthreads();
        if (kb + 1 < NKB) {
            a0 = ap0[(kb + 1) * 4];
            a1 = ap1[(kb + 1) * 4];
            b0 = bp0[(kb + 1) * 4];
            b1 = bp1[(kb + 1) * 4];
        }
        short8 af[4], bfr[4];
#pragma unroll
        for (int i = 0; i < 4; ++i)
            af[i] = *(const short8*)&As[(wr * 64 + i * 16 + r) * PK + g * 8];
#pragma unroll
        for (int j = 0; j < 4; ++j)
            bfr[j] = *(const short8*)&Bs[(wc * 64 + j * 16 + r) * PK + g * 8];
#pragma unroll
        for (int i = 0; i < 4; ++i)
#pragma unroll
            for (int j = 0; j < 4; ++j)
                acc[i][j] = __builtin_amdgcn_mfma_f32_16x16x32_bf16(af[i], bfr[j],
                                                                    acc[i][j], 0, 0, 0);
    }

    // epilogue: row=(lane>>4)*4+reg, col=lane&15 within each 16x16 tile
#pragma unroll
    for (int i = 0; i < 4; ++i) {
        int rowb = m0 + wr * 64 + i * 16 + g * 4;
#pragma unroll
        for (int j = 0; j < 4; ++j) {
            int cb = n0 + wc * 64 + j * 16 + r;
            float bv = TANH ? bias[cb] : 0.0f;
#pragma unroll
            for (int rr = 0; rr < 4; ++rr) {
                int row = rowb + rr;
                if (row < N) {
                    float v = acc[i][j][rr];
                    if (TANH) v = fast_tanh(v + bv);
                    C[(size_t)row * 256 + cb] = f2bf(v);
                }
            }
        }
    }
}

// ---------------- pooling (sorted batch index, run-flush), bf16 input -------
#define POOL_CHUNK 256
__global__ void pool_kernel(const unsigned short* __restrict__ act,
                            const int* __restrict__ batch,
                            float* __restrict__ gsum, unsigned* __restrict__ gmaxk,
                            int* __restrict__ gcnt, int N) {
    int t  = threadIdx.x;   // 256 = DDIM
    int n0 = blockIdx.x * POOL_CHUNK;
    if (n0 >= N) return;
    int n1 = n0 + POOL_CHUNK;
    if (n1 > N) n1 = N;
    int   cur = batch[n0];
    float sum = 0.0f, mx = -2.0f;
    int   run = 0;
    for (int n = n0; n < n1; ++n) {
        int g = batch[n];
        float v = bf2f(act[(size_t)n * DDIM + t]);
        if (g != cur) {
            atomicAdd(&gsum[cur * DDIM + t], sum);
            atomicMax(&gmaxk[cur * DDIM + t], f2key(mx));
            if (t == 0) atomicAdd(&gcnt[cur], run);
            cur = g; sum = 0.0f; mx = -2.0f; run = 0;
        }
        sum += v;
        mx = fmaxf(mx, v);
        run++;
    }
    atomicAdd(&gsum[cur * DDIM + t], sum);
    atomicMax(&gmaxk[cur * DDIM + t], f2key(mx));
    if (t == 0) atomicAdd(&gcnt[cur], run);
}

// ---------------- fused MLP (one WG per graph), fp32 ----------------
__global__ void mlp_kernel(const float* __restrict__ gsum, const unsigned* __restrict__ gmaxk,
                           const int* __restrict__ gcnt,
                           const float* __restrict__ fc1_w, const float* __restrict__ fc1_b,
                           const float* __restrict__ fc2_w, const float* __restrict__ fc2_b,
                           const float* __restrict__ out_w, const float* __restrict__ out_b,
                           float* __restrict__ out) {
    int g = blockIdx.x;
    int t = threadIdx.x;   // 256
    __shared__ float gv[512];
    __shared__ float t1[512];
    __shared__ float t2[256];
    float cnt = fmaxf((float)gcnt[g], 1.0f);
    gv[t]       = key2f(gmaxk[g * DDIM + t]);
    gv[256 + t] = gsum[g * DDIM + t] / cnt;
    __syncthreads();
    float a0 = fc1_b[t], a1 = fc1_b[t + 256];
    for (int k = 0; k < 512; ++k) {
        float gk = gv[k];
        a0 = fmaf(gk, fc1_w[k * 512 + t], a0);
        a1 = fmaf(gk, fc1_w[k * 512 + t + 256], a1);
    }
    t1[t]       = fmaxf(a0, 0.0f);
    t1[t + 256] = fmaxf(a1, 0.0f);
    __syncthreads();
    float b0 = fc2_b[t];
    for (int k = 0; k < 512; ++k)
        b0 = fmaf(t1[k], fc2_w[k * 256 + t], b0);
    t2[t] = fmaxf(b0, 0.0f);
    __syncthreads();
    if (t < 10) {
        float o = out_b[t];
        for (int k = 0; k < 256; ++k)
            o = fmaf(t2[k], out_w[k * 10 + t], o);
        out[g * 10 + t] = o;
    }
}

// ---------------------------------------------------------------------------
extern "C" void kernel_launch(void* const* d_in, const int* in_sizes, int n_in,
                              void* d_out, int out_size, void* d_ws, size_t ws_size,
                              hipStream_t stream) {
    const float* x      = (const float*)d_in[0];
    const int*   ei     = (const int*)d_in[1];
    const int*   batch  = (const int*)d_in[2];
    const float* W0     = (const float*)d_in[3];
    const float* b0     = (const float*)d_in[4];
    const float* W1     = (const float*)d_in[5];
    const float* b1     = (const float*)d_in[6];
    const float* W2     = (const float*)d_in[7];
    const float* b2     = (const float*)d_in[8];
    const float* W3     = (const float*)d_in[9];
    const float* b3     = (const float*)d_in[10];
    const float* fc1_w  = (const float*)d_in[11];
    const float* fc1_b  = (const float*)d_in[12];
    const float* fc2_w  = (const float*)d_in[13];
    const float* fc2_b  = (const float*)d_in[14];
    const float* out_w  = (const float*)d_in[15];
    const float* out_b  = (const float*)d_in[16];
    float* out = (float*)d_out;

    const int N = in_sizes[2];          // 50000
    const int E = in_sizes[1] / 2;      // 1600000

    // workspace layout (bytes)
    char* ws = (char*)d_ws;
    const size_t off_deg    = 0;          // 200000
    const size_t off_gsum   = 200192;     // 65536
    const size_t off_gmaxk  = 265728;     // 65536
    const size_t off_gcnt   = 331264;     // 256
    const size_t ZERO_BYTES = 331776;
    const size_t off_dis    = 331776;     // 200000
    const size_t off_rowptr = 531968;     // 200000
    const size_t off_cursor = 732160;     // 200000
    const size_t off_col    = 932352;     // 6400000
    const size_t off_norm   = 7332352;    // 6400000
    const size_t off_xh     = 13732352;   // N*128*2 = 12800000
    const size_t off_wt0    = 26532352;   // 256*128*2 = 65536
    const size_t off_wt1    = 26597888;   // 256*256*2 = 131072
    const size_t off_wt2    = 26728960;   // 131072
    const size_t off_wt3    = 26860032;   // 131072
    const size_t off_bufA   = 26991104;   // N*256*2 = 25600000
    const size_t off_bufB   = 52591104;   // 25600000  (end ~78.2 MB)

    int*            deg    = (int*)(ws + off_deg);
    float*          gsum   = (float*)(ws + off_gsum);
    unsigned*       gmaxk  = (unsigned*)(ws + off_gmaxk);
    int*            gcnt   = (int*)(ws + off_gcnt);
    float*          dis    = (float*)(ws + off_dis);
    int*            rowptr = (int*)(ws + off_rowptr);
    int*            cursor = (int*)(ws + off_cursor);
    int*            col    = (int*)(ws + off_col);
    float*          normv  = (float*)(ws + off_norm);
    unsigned short* xh     = (unsigned short*)(ws + off_xh);
    short*          wt0    = (short*)(ws + off_wt0);
    short*          wt1    = (short*)(ws + off_wt1);
    short*          wt2    = (short*)(ws + off_wt2);
    short*          wt3    = (short*)(ws + off_wt3);
    unsigned short* bufA   = (unsigned short*)(ws + off_bufA);
    unsigned short* bufB   = (unsigned short*)(ws + off_bufB);

    hipMemsetAsync(ws, 0, ZERO_BYTES, stream);

    // CSR build
    hist_kernel<<<(E + 255) / 256, 256, 0, stream>>>(ei, deg, E);
    dis_kernel<<<(N + 255) / 256, 256, 0, stream>>>(deg, dis, N);
    scan_kernel<<<1, 1024, 0, stream>>>(deg, rowptr, cursor, N);
    scatter_kernel<<<(E + 255) / 256, 256, 0, stream>>>(ei, cursor, col, normv, dis, E);

    // casts
    cast_x_kernel<<<(N * 128 + 255) / 256, 256, 0, stream>>>(x, xh, N * 128);
    transpose_w_kernel<<<128, 256, 0, stream>>>(W0, (unsigned short*)wt0, 128);
    transpose_w_kernel<<<256, 256, 0, stream>>>(W1, (unsigned short*)wt1, 256);
    transpose_w_kernel<<<256, 256, 0, stream>>>(W2, (unsigned short*)wt2, 256);
    transpose_w_kernel<<<256, 256, 0, stream>>>(W3, (unsigned short*)wt3, 256);

    // layer 0 (reordered): agg = A_hat @ x (bf16, 128-dim), then tanh(agg@W0+b0)
    msgpass_bf16<128, false><<<(N + 3) / 4, 256, 0, stream>>>(
        xh, bufB, rowptr, deg, col, normv, dis, nullptr);
    gemm_mfma<128, true><<<dim3((N + 127) / 128, 2), 256, 0, stream>>>(
        (const short*)bufB, wt0, b0, bufA, N);

    // layers 1..3: hW = h @ W (bf16); h = tanh(A_hat hW + b)
    const short* wts[3] = {wt1, wt2, wt3};
    const float* bs_[3] = {b1, b2, b3};
    for (int l = 0; l < 3; ++l) {
        gemm_mfma<256, false><<<dim3((N + 127) / 128, 2), 256, 0, stream>>>(
            (const short*)bufA, wts[l], nullptr, bufB, N);
        msgpass_bf16<256, true><<<(N + 3) / 4, 256, 0, stream>>>(
            bufB, bufA, rowptr, deg, col, normv, dis, bs_[l]);
    }

    // pooling + MLP (fp32)
    pool_kernel<<<(N + POOL_CHUNK - 1) / POOL_CHUNK, 256, 0, stream>>>(
        bufA, batch, gsum, gmaxk, gcnt, N);
    mlp_kernel<<<64, 256, 0, stream>>>(gsum, gmaxk, gcnt, fc1_w, fc1_b, fc2_w, fc2_b,
                                       out_w, out_b, out);
}